// Round 6
// baseline (78.735 us; speedup 1.0000x reference)
//
#include <hip/hip_runtime.h>
#include <hip/hip_bf16.h>

typedef __attribute__((ext_vector_type(8))) _Float16 half8;
typedef __attribute__((ext_vector_type(4))) _Float16 half4;
typedef __attribute__((ext_vector_type(4))) float f32x4;

#define MFMAH(a,b,c) __builtin_amdgcn_mfma_f32_16x16x32_f16(a,b,c,0,0,0)

#define LOG2_10K_64 0.2076205059304595f
#define INV2PI 0.15915494309189535f

// ---------------------------------------------------------------------------
// Prep: W1 -> W1t[n][k] f16; Wq/Wk/Wv -> transposed f16; Pe[2048][2048] f16
// pos-enc table (Pe[s][j] = j even ? sin : cos of s/10000^((j>>1)/64)).
// Grid: 64 transpose + 192 qkv + 1024 Pe blocks.
// ---------------------------------------------------------------------------
__global__ __launch_bounds__(256) void k_prep(const float* __restrict__ W1,
                                              const float* __restrict__ Wq,
                                              const float* __restrict__ Wk,
                                              const float* __restrict__ Wv,
                                              _Float16* __restrict__ W1t,
                                              _Float16* __restrict__ Wqkvt,
                                              _Float16* __restrict__ Pe) {
  const int bid = blockIdx.x, tid = threadIdx.x;
  if (bid < 64) {
    __shared__ float Tl[64][65];
    const int kt0 = (bid >> 1) * 64, nt0 = (bid & 1) * 64;
    const int row = tid >> 2, c0 = (tid & 3) * 16;
#pragma unroll
    for (int e = 0; e < 16; e += 4) {
      float4 f = *(const float4*)(W1 + (size_t)(kt0 + row) * 128 + nt0 + c0 + e);
      Tl[row][c0 + e] = f.x; Tl[row][c0 + e + 1] = f.y;
      Tl[row][c0 + e + 2] = f.z; Tl[row][c0 + e + 3] = f.w;
    }
    __syncthreads();
    const int nrow = tid >> 2, kc0 = (tid & 3) * 16;
    _Float16* wp = W1t + (size_t)(nt0 + nrow) * 2048 + kt0 + kc0;
#pragma unroll
    for (int e = 0; e < 16; ++e) wp[e] = (_Float16)Tl[kc0 + e][nrow];
  } else if (bid < 256) {
    int r = (bid - 64) * 256 + tid;
    if (r < 3 * 16384) {
      int m = r >> 14, e = r & 16383;
      int n = e >> 7, k = e & 127;
      const float* W = (m == 0) ? Wq : (m == 1) ? Wk : Wv;
      Wqkvt[r] = (_Float16)W[k * 128 + n];
    }
  } else {
    // Pe table: thread -> 16 contiguous elems of row s
    const int g = (bid - 256) * 256 + tid;      // 0..262143
    const int s = g >> 7;
    const int j0 = (g & 127) * 16;
    const float sf = (float)s;
    half8 o0, o1;
#pragma unroll
    for (int p = 0; p < 8; ++p) {
      const int jh = (j0 >> 1) + p;
      float c = exp2f((float)jh * -LOG2_10K_64) * INV2PI;
      float r = __builtin_fmaf(sf, c, -rintf(sf * c));
      _Float16 sn = (_Float16)__builtin_amdgcn_sinf(r);
      _Float16 cs = (_Float16)__builtin_amdgcn_cosf(r);
      if (p < 4) { o0[2 * p] = sn; o0[2 * p + 1] = cs; }
      else       { o1[2 * (p - 4)] = sn; o1[2 * (p - 4) + 1] = cs; }
    }
    _Float16* dst = Pe + (size_t)s * 2048 + j0;
    *(half8*)dst = o0;
    *(half8*)(dst + 8) = o1;
  }
}

// ---------------------------------------------------------------------------
// Fused GEMM1 + QKV, barrier-free K-loop.
// Block = 16 rows, 8 waves = 4 k-groups x 2 col-groups. Wave (kg,cg):
// rows i0..i0+15, cols cg*64..cg*64+63 (4 MFMA col-tiles), k in [512kg,512kg+512).
// A-fragments built in registers from x (f32) + Pe (f16 table); B direct from
// n-major W1t (L2). No LDS / no barriers until the split-k reduce.
// ---------------------------------------------------------------------------
__global__ __launch_bounds__(512) void k_fused(const float* __restrict__ x,
                                               const _Float16* __restrict__ W1t,
                                               const _Float16* __restrict__ Pe,
                                               const _Float16* __restrict__ Wqkv,
                                               const float* __restrict__ b1,
                                               _Float16* __restrict__ Qg,
                                               _Float16* __restrict__ Kg,
                                               _Float16* __restrict__ Vg) {
  __shared__ float Hp[4][16][132];       // split-k partials (+4 pad)
  __shared__ _Float16 Hs[16][136];       // reduced h tile, f16
  const int tid = threadIdx.x;
  const int lane = tid & 63, wv = tid >> 6;
  const int kg = wv >> 1, cg = wv & 1;
  const int fr = lane & 15, kg8 = (lane >> 4) * 8;
  const int i0 = blockIdx.x * 16;

  const float*    xs  = x   + (size_t)(i0 + fr) * 2048 + kg * 512 + kg8;
  const _Float16* pes = Pe  + (size_t)((i0 + fr) & 2047) * 2048 + kg * 512 + kg8;
  const _Float16* ws  = W1t + (size_t)(cg * 64 + fr) * 2048 + kg * 512 + kg8;

  f32x4 acc[4] = {};
#pragma unroll 1
  for (int s = 0; s < 4; ++s) {          // 4 steps x 128 k, no barriers
#pragma unroll
    for (int kk = 0; kk < 4; ++kk) {
      f32x4 x0 = *(const f32x4*)(xs + kk * 32);
      f32x4 x1 = *(const f32x4*)(xs + kk * 32 + 4);
      half8 pe = *(const half8*)(pes + kk * 32);
      half8 af;
#pragma unroll
      for (int e = 0; e < 4; ++e) af[e] = (_Float16)(x0[e] + (float)pe[e]);
#pragma unroll
      for (int e = 0; e < 4; ++e) af[4 + e] = (_Float16)(x1[e] + (float)pe[4 + e]);
#pragma unroll
      for (int ct = 0; ct < 4; ++ct) {
        half8 b = *(const half8*)(ws + ct * 32768 + kk * 32);
        acc[ct] = MFMAH(af, b, acc[ct]);
      }
    }
    xs += 128; pes += 128; ws += 128;
  }

  // split-k partials -> LDS
#pragma unroll
  for (int ct = 0; ct < 4; ++ct)
#pragma unroll
    for (int r = 0; r < 4; ++r)
      Hp[kg][(lane >> 4) * 4 + r][cg * 64 + ct * 16 + fr] = acc[ct][r];
  __syncthreads();

  // reduce 4 k-groups + bias + relu -> Hs f16 (512 thr x 4 elems)
  {
    const int row = tid >> 5, col = (tid & 31) * 4;
    f32x4 v = *(const f32x4*)&Hp[0][row][col];
#pragma unroll
    for (int k2 = 1; k2 < 4; ++k2) {
      f32x4 p = *(const f32x4*)&Hp[k2][row][col];
#pragma unroll
      for (int e = 0; e < 4; ++e) v[e] += p[e];
    }
    half4 hv;
#pragma unroll
    for (int e = 0; e < 4; ++e) {
      float t = v[e] + b1[col + e];
      hv[e] = (_Float16)(t > 0.f ? t : 0.f);
    }
    *(half4*)&Hs[row][col] = hv;
  }
  __syncthreads();

  // QKV: wave wv owns output cols wv*16..wv*16+15 for each of Q,K,V
  const _Float16* wqrow = Wqkv + (size_t)(wv * 16 + fr) * 128 + kg8;
#pragma unroll 1
  for (int m = 0; m < 3; ++m) {
    f32x4 a2 = {};
#pragma unroll
    for (int kk = 0; kk < 4; ++kk) {
      half8 a = *(const half8*)&Hs[fr][kk * 32 + kg8];
      half8 b = *(const half8*)(wqrow + m * 16384 + kk * 32);
      a2 = MFMAH(a, b, a2);
    }
    _Float16* dst = (m == 0) ? Qg : (m == 1) ? Kg : Vg;
#pragma unroll
    for (int r = 0; r < 4; ++r)
      dst[(size_t)(i0 + (lane >> 4) * 4 + r) * 128 + wv * 16 + fr] = (_Float16)a2[r];
  }
}

// ---------------------------------------------------------------------------
// Attention via MFMA. Block = 16 q-rows of one batch; 4 waves; grid 512.
// K-window: lr in [0,80) <-> j = i0-32+lr (zero rows outside sequence ->
// score 0, INCLUDED in softmax, matching reference zero-padding).
// Band mask: q-row r keeps cols lr in [r, r+64] (65 entries).
// ---------------------------------------------------------------------------
__global__ __launch_bounds__(256) void k_attn(const _Float16* __restrict__ Qg,
                                              const _Float16* __restrict__ Kg,
                                              const _Float16* __restrict__ Vg,
                                              const float* __restrict__ Wo,
                                              const float* __restrict__ bo,
                                              float* __restrict__ outp,
                                              float* __restrict__ attwg) {
  __shared__ _Float16 Qs[16][136];
  __shared__ _Float16 Ks[80][136];
  __shared__ _Float16 Vs[96][136];
  __shared__ _Float16 Ps[16][104];
  __shared__ float sc[16][84];
  __shared__ float aw[16 * 65];
  __shared__ float wol[128][2];
  __shared__ float proj[4][16][2];
  const int tid = threadIdx.x;
  const int lane = tid & 63, wv = tid >> 6;
  const int b = blockIdx.x >> 7;
  const int i0 = (blockIdx.x & 127) << 4;
  const int rowbase = b * 2048 + i0;
  const float invscale = 0.08838834764831845f;  // 1/sqrt(128)

  {
    const int row = tid >> 4, d8 = (tid & 15) * 8;
    *(half8*)&Qs[row][d8] = *(const half8*)(Qg + (size_t)(rowbase + row) * 128 + d8);
  }
#pragma unroll
  for (int it = 0; it < 5; ++it) {
    const int idx = it * 256 + tid;
    const int lr = idx >> 4, d8 = (idx & 15) * 8;
    const int j = i0 - 32 + lr;
    half8 kv = {0, 0, 0, 0, 0, 0, 0, 0};
    if (j >= 0 && j < 2048)
      kv = *(const half8*)(Kg + (size_t)(b * 2048 + j) * 128 + d8);
    *(half8*)&Ks[lr][d8] = kv;
  }
#pragma unroll
  for (int it = 0; it < 6; ++it) {
    const int idx = it * 256 + tid;
    const int lr = idx >> 4, d8 = (idx & 15) * 8;
    const int j = i0 - 32 + lr;
    half8 vv = {0, 0, 0, 0, 0, 0, 0, 0};
    if (lr < 80 && j >= 0 && j < 2048)
      vv = *(const half8*)(Vg + (size_t)(b * 2048 + j) * 128 + d8);
    *(half8*)&Vs[lr][d8] = vv;
  }
  wol[tid >> 1][tid & 1] = Wo[tid];
  __syncthreads();

  const int fr = lane & 15, kg8 = (lane >> 4) * 8;
  // QK^T: C[16 q][80 k] = 5 col-tiles
  {
    const int nct = (wv == 0) ? 2 : 1;
    for (int p = 0; p < nct; ++p) {
      const int ct = (p == 0) ? wv : 4;
      f32x4 acc = {};
#pragma unroll
      for (int kk = 0; kk < 4; ++kk) {
        half8 a  = *(const half8*)&Qs[fr][kk * 32 + kg8];
        half8 bb = *(const half8*)&Ks[ct * 16 + fr][kk * 32 + kg8];
        acc = MFMAH(a, bb, acc);
      }
#pragma unroll
      for (int r = 0; r < 4; ++r)
        sc[(lane >> 4) * 4 + r][ct * 16 + fr] = acc[r] * invscale;
    }
  }
  __syncthreads();

  // banded softmax; wave wv owns q-rows 4wv..4wv+3
#pragma unroll 1
  for (int rr = 0; rr < 4; ++rr) {
    const int r = wv * 4 + rr;
    const int c0 = lane;
    const bool ib0 = (c0 >= r);
    const bool ib1 = (lane <= r);
    float a0 = ib0 ? sc[r][c0] : -1e30f;
    float a1 = ib1 ? sc[r][64 + lane] : -1e30f;
    float mx = fmaxf(a0, a1);
#pragma unroll
    for (int o = 1; o < 64; o <<= 1) mx = fmaxf(mx, __shfl_xor(mx, o));
    float e0 = ib0 ? __expf(a0 - mx) : 0.f;
    float e1 = ib1 ? __expf(a1 - mx) : 0.f;
    float sm = e0 + e1;
#pragma unroll
    for (int o = 1; o < 64; o <<= 1) sm += __shfl_xor(sm, o);
    const float inv = 1.0f / sm;
    const float w0 = e0 * inv, w1 = e1 * inv;
    if (ib0) aw[r * 65 + (r + 64 - c0)] = w0;
    if (ib1) aw[r * 65 + (r - lane)] = w1;
    Ps[r][c0] = (_Float16)w0;
    if (lane < 32) Ps[r][64 + lane] = (_Float16)((lane < 16) ? w1 : 0.f);
  }
  __syncthreads();

  for (int i = tid; i < 1040; i += 256)
    attwg[(size_t)rowbase * 65 + i] = aw[i];

  // PV: C2[16 q][128 d] = P(16x96) @ V(96x128)
  f32x4 c2[2] = {};
#pragma unroll
  for (int kk = 0; kk < 3; ++kk) {
    half8 a = *(const half8*)&Ps[fr][kk * 32 + kg8];
#pragma unroll
    for (int dt2 = 0; dt2 < 2; ++dt2) {
      const int d = (2 * wv + dt2) * 16 + fr;
      half8 bb;
#pragma unroll
      for (int e = 0; e < 8; ++e) bb[e] = Vs[kk * 32 + kg8 + e][d];
      c2[dt2] = MFMAH(a, bb, c2[dt2]);
    }
  }
  // projection
#pragma unroll
  for (int r = 0; r < 4; ++r) {
    float p0 = 0.f, p1 = 0.f;
#pragma unroll
    for (int dt2 = 0; dt2 < 2; ++dt2) {
      const int d = (2 * wv + dt2) * 16 + fr;
      p0 += c2[dt2][r] * wol[d][0];
      p1 += c2[dt2][r] * wol[d][1];
    }
    p0 += __shfl_xor(p0, 1); p0 += __shfl_xor(p0, 2);
    p0 += __shfl_xor(p0, 4); p0 += __shfl_xor(p0, 8);
    p1 += __shfl_xor(p1, 1); p1 += __shfl_xor(p1, 2);
    p1 += __shfl_xor(p1, 4); p1 += __shfl_xor(p1, 8);
    if (fr == 0) {
      const int q = (lane >> 4) * 4 + r;
      proj[wv][q][0] = p0;
      proj[wv][q][1] = p1;
    }
  }
  __syncthreads();
  if (tid < 16) {
    float s0 = proj[0][tid][0] + proj[1][tid][0] + proj[2][tid][0] + proj[3][tid][0];
    float s1 = proj[0][tid][1] + proj[1][tid][1] + proj[2][tid][1] + proj[3][tid][1];
    outp[((size_t)rowbase + tid) * 2 + 0] = s0 * invscale + bo[0];
    outp[((size_t)rowbase + tid) * 2 + 1] = s1 * invscale + bo[1];
  }
}

extern "C" void kernel_launch(void* const* d_in, const int* in_sizes, int n_in,
                              void* d_out, int out_size, void* d_ws, size_t ws_size,
                              hipStream_t stream) {
  const float* x  = (const float*)d_in[0];
  const float* W1 = (const float*)d_in[1];
  const float* b1 = (const float*)d_in[2];
  const float* Wq = (const float*)d_in[3];
  const float* Wk = (const float*)d_in[4];
  const float* Wv = (const float*)d_in[5];
  const float* Wo = (const float*)d_in[6];
  const float* bo = (const float*)d_in[7];
  float* out  = (float*)d_out;            // (4,2048,2)
  float* attw = out + 16384;              // (4,2048,65)

  _Float16* W1t  = (_Float16*)d_ws;       // 128x2048
  _Float16* Wqkv = W1t + 262144;          // 3 x 128x128
  _Float16* Pe   = Wqkv + 49152;          // 2048x2048 pos-enc table
  _Float16* Qg   = Pe + 4194304;          // 8192x128
  _Float16* Kg   = Qg + 1048576;
  _Float16* Vg   = Kg + 1048576;

  k_prep<<<1280, 256, 0, stream>>>(W1, Wq, Wk, Wv, W1t, Wqkv, Pe);
  k_fused<<<512, 512, 0, stream>>>(x, W1t, Pe, Wqkv, b1, Qg, Kg, Vg);
  k_attn<<<512, 256, 0, stream>>>(Qg, Kg, Vg, Wo, bo, out, attw);
}

// Round 7
// 66.670 us; speedup vs baseline: 1.1810x; 1.1810x over previous
//
#include <hip/hip_runtime.h>
#include <hip/hip_bf16.h>

typedef __attribute__((ext_vector_type(8))) _Float16 half8;
typedef __attribute__((ext_vector_type(4))) _Float16 half4;
typedef __attribute__((ext_vector_type(4))) float f32x4;

#define MFMAH(a,b,c) __builtin_amdgcn_mfma_f32_16x16x32_f16(a,b,c,0,0,0)

#define LOG2_10K_64 0.2076205059304595f
#define INV2PI 0.15915494309189535f

// ---------------------------------------------------------------------------
// Prep: W1 -> W1t[n][k] f16; Wq/Wk/Wv -> transposed f16; Pe[2048][2048] f16
// pos-enc table. Grid: 64 transpose + 192 qkv + 1024 Pe blocks.
// ---------------------------------------------------------------------------
__global__ __launch_bounds__(256) void k_prep(const float* __restrict__ W1,
                                              const float* __restrict__ Wq,
                                              const float* __restrict__ Wk,
                                              const float* __restrict__ Wv,
                                              _Float16* __restrict__ W1t,
                                              _Float16* __restrict__ Wqkvt,
                                              _Float16* __restrict__ Pe) {
  const int bid = blockIdx.x, tid = threadIdx.x;
  if (bid < 64) {
    __shared__ float Tl[64][65];
    const int kt0 = (bid >> 1) * 64, nt0 = (bid & 1) * 64;
    const int row = tid >> 2, c0 = (tid & 3) * 16;
#pragma unroll
    for (int e = 0; e < 16; e += 4) {
      float4 f = *(const float4*)(W1 + (size_t)(kt0 + row) * 128 + nt0 + c0 + e);
      Tl[row][c0 + e] = f.x; Tl[row][c0 + e + 1] = f.y;
      Tl[row][c0 + e + 2] = f.z; Tl[row][c0 + e + 3] = f.w;
    }
    __syncthreads();
    const int nrow = tid >> 2, kc0 = (tid & 3) * 16;
    _Float16* wp = W1t + (size_t)(nt0 + nrow) * 2048 + kt0 + kc0;
#pragma unroll
    for (int e = 0; e < 16; ++e) wp[e] = (_Float16)Tl[kc0 + e][nrow];
  } else if (bid < 256) {
    int r = (bid - 64) * 256 + tid;
    if (r < 3 * 16384) {
      int m = r >> 14, e = r & 16383;
      int n = e >> 7, k = e & 127;
      const float* W = (m == 0) ? Wq : (m == 1) ? Wk : Wv;
      Wqkvt[r] = (_Float16)W[k * 128 + n];
    }
  } else {
    const int g = (bid - 256) * 256 + tid;      // 0..262143
    const int s = g >> 7;
    const int j0 = (g & 127) * 16;
    const float sf = (float)s;
    half8 o0, o1;
#pragma unroll
    for (int p = 0; p < 8; ++p) {
      const int jh = (j0 >> 1) + p;
      float c = exp2f((float)jh * -LOG2_10K_64) * INV2PI;
      float r = __builtin_fmaf(sf, c, -rintf(sf * c));
      _Float16 sn = (_Float16)__builtin_amdgcn_sinf(r);
      _Float16 cs = (_Float16)__builtin_amdgcn_cosf(r);
      if (p < 4) { o0[2 * p] = sn; o0[2 * p + 1] = cs; }
      else       { o1[2 * (p - 4)] = sn; o1[2 * (p - 4) + 1] = cs; }
    }
    _Float16* dst = Pe + (size_t)s * 2048 + j0;
    *(half8*)dst = o0;
    *(half8*)(dst + 8) = o1;
  }
}

// ---------------------------------------------------------------------------
// Fused GEMM1 + QKV, ONE staging barrier for the whole K-loop.
// Block = 16 rows x full K (2048). Stage A = x+Pe -> f16 LDS (64 KB,
// XOR-swizzled 16B units: u ^= row&7) in one coalesced burst; ONE barrier;
// then barrier-free MFMA phase: 8 waves = 4 kg (k-split) x 2 cg (col-split),
// B fragments streamed direct from n-major W1t (L2). Split-k reduce + QKV
// epilogue. Grid 512, 512 threads, 2 blocks/CU.
// ---------------------------------------------------------------------------
__global__ __launch_bounds__(512, 4) void k_fused(const float* __restrict__ x,
                                                  const _Float16* __restrict__ W1t,
                                                  const _Float16* __restrict__ Pe,
                                                  const _Float16* __restrict__ Wqkv,
                                                  const float* __restrict__ b1,
                                                  _Float16* __restrict__ Qg,
                                                  _Float16* __restrict__ Kg,
                                                  _Float16* __restrict__ Vg) {
  __shared__ __align__(16) char smem[65536];
  const int tid = threadIdx.x;
  const int lane = tid & 63, wv = tid >> 6;
  const int fr = lane & 15, hi = lane >> 4, kg8 = hi * 8;
  const int i0 = blockIdx.x * 16;

  // ---- stage A: rows i0..i0+15, all 2048 k, coalesced, swizzled ----
  {
    const int ar = tid >> 5;                  // row 0..15
    const int alc = (tid & 31) * 4;           // col base
    const float* xr = x + (size_t)(i0 + ar) * 2048;
    const _Float16* per = Pe + (size_t)((i0 + ar) & 2047) * 2048;
    const int rsw = ar & 7;
    const int hb = (alc & 7) * 2;             // 0 or 8 byte sub-offset
    char* arow_base = smem + ar * 4096;
#pragma unroll
    for (int j = 0; j < 16; ++j) {
      const int c = alc + j * 128;
      float4 xv = *(const float4*)(xr + c);
      half4 pv = *(const half4*)(per + c);
      half4 av;
      av[0] = (_Float16)(xv.x + (float)pv[0]);
      av[1] = (_Float16)(xv.y + (float)pv[1]);
      av[2] = (_Float16)(xv.z + (float)pv[2]);
      av[3] = (_Float16)(xv.w + (float)pv[3]);
      const int u = (c >> 3) ^ rsw;
      *(half4*)(arow_base + u * 16 + hb) = av;
    }
  }
  __syncthreads();

  // ---- barrier-free MFMA phase: wave (kg,cg) covers k [512kg,512kg+512),
  //      cols cg*64..cg*64+63 (4 tiles) ----
  const int kg = wv >> 1, cg = wv & 1;
  const _Float16* ws = W1t + (size_t)(cg * 64 + fr) * 2048 + kg * 512 + kg8;
  const char* abase = smem + fr * 4096;
  const int usw = fr & 7;
  f32x4 acc[4] = {};
#pragma unroll 2
  for (int ks = 0; ks < 16; ++ks) {
    const int u = (kg * 64 + ks * 4 + hi) ^ usw;
    half8 a = *(const half8*)(abase + u * 16);
#pragma unroll
    for (int ct = 0; ct < 4; ++ct) {
      half8 b = *(const half8*)(ws + ct * 32768 + ks * 32);
      acc[ct] = MFMAH(a, b, acc[ct]);
    }
  }
  __syncthreads();   // all A reads done; overlay Hp on smem

  // ---- split-k partials -> LDS ----
  float (*Hp)[16][132] = (float(*)[16][132])smem;
#pragma unroll
  for (int ct = 0; ct < 4; ++ct)
#pragma unroll
    for (int r = 0; r < 4; ++r)
      Hp[kg][hi * 4 + r][cg * 64 + ct * 16 + fr] = acc[ct][r];
  __syncthreads();

  // ---- reduce 4 kg + bias + relu -> Hs f16 ----
  _Float16 (*Hs)[136] = (_Float16(*)[136])(smem + 33792);
  {
    const int row = tid >> 5, col = (tid & 31) * 4;
    f32x4 v = *(const f32x4*)&Hp[0][row][col];
#pragma unroll
    for (int k2 = 1; k2 < 4; ++k2) {
      f32x4 p = *(const f32x4*)&Hp[k2][row][col];
#pragma unroll
      for (int e = 0; e < 4; ++e) v[e] += p[e];
    }
    half4 hv;
#pragma unroll
    for (int e = 0; e < 4; ++e) {
      float t = v[e] + b1[col + e];
      hv[e] = (_Float16)(t > 0.f ? t : 0.f);
    }
    *(half4*)&Hs[row][col] = hv;
  }
  __syncthreads();

  // ---- QKV: wave wv owns output cols wv*16..wv*16+15 ----
  const _Float16* wqrow = Wqkv + (size_t)(wv * 16 + fr) * 128 + kg8;
#pragma unroll 1
  for (int m = 0; m < 3; ++m) {
    f32x4 a2 = {};
#pragma unroll
    for (int kk = 0; kk < 4; ++kk) {
      half8 a = *(const half8*)&Hs[fr][kk * 32 + kg8];
      half8 b = *(const half8*)(wqrow + m * 16384 + kk * 32);
      a2 = MFMAH(a, b, a2);
    }
    _Float16* dst = (m == 0) ? Qg : (m == 1) ? Kg : Vg;
#pragma unroll
    for (int r = 0; r < 4; ++r)
      dst[(size_t)(i0 + hi * 4 + r) * 128 + wv * 16 + fr] = (_Float16)a2[r];
  }
}

// ---------------------------------------------------------------------------
// Attention via MFMA. Block = 16 q-rows of one batch; 4 waves; grid 512.
// Zero K-rows outside sequence -> score 0 (included), matching reference.
// ---------------------------------------------------------------------------
__global__ __launch_bounds__(256) void k_attn(const _Float16* __restrict__ Qg,
                                              const _Float16* __restrict__ Kg,
                                              const _Float16* __restrict__ Vg,
                                              const float* __restrict__ Wo,
                                              const float* __restrict__ bo,
                                              float* __restrict__ outp,
                                              float* __restrict__ attwg) {
  __shared__ _Float16 Qs[16][136];
  __shared__ _Float16 Ks[80][136];
  __shared__ _Float16 Vs[96][136];
  __shared__ _Float16 Ps[16][104];
  __shared__ float sc[16][84];
  __shared__ float aw[16 * 65];
  __shared__ float wol[128][2];
  __shared__ float proj[4][16][2];
  const int tid = threadIdx.x;
  const int lane = tid & 63, wv = tid >> 6;
  const int b = blockIdx.x >> 7;
  const int i0 = (blockIdx.x & 127) << 4;
  const int rowbase = b * 2048 + i0;
  const float invscale = 0.08838834764831845f;  // 1/sqrt(128)

  {
    const int row = tid >> 4, d8 = (tid & 15) * 8;
    *(half8*)&Qs[row][d8] = *(const half8*)(Qg + (size_t)(rowbase + row) * 128 + d8);
  }
#pragma unroll
  for (int it = 0; it < 5; ++it) {
    const int idx = it * 256 + tid;
    const int lr = idx >> 4, d8 = (idx & 15) * 8;
    const int j = i0 - 32 + lr;
    half8 kv = {0, 0, 0, 0, 0, 0, 0, 0};
    if (j >= 0 && j < 2048)
      kv = *(const half8*)(Kg + (size_t)(b * 2048 + j) * 128 + d8);
    *(half8*)&Ks[lr][d8] = kv;
  }
#pragma unroll
  for (int it = 0; it < 6; ++it) {
    const int idx = it * 256 + tid;
    const int lr = idx >> 4, d8 = (idx & 15) * 8;
    const int j = i0 - 32 + lr;
    half8 vv = {0, 0, 0, 0, 0, 0, 0, 0};
    if (lr < 80 && j >= 0 && j < 2048)
      vv = *(const half8*)(Vg + (size_t)(b * 2048 + j) * 128 + d8);
    *(half8*)&Vs[lr][d8] = vv;
  }
  wol[tid >> 1][tid & 1] = Wo[tid];
  __syncthreads();

  const int fr = lane & 15, kg8 = (lane >> 4) * 8;
  // QK^T: C[16 q][80 k] = 5 col-tiles
  {
    const int nct = (wv == 0) ? 2 : 1;
    for (int p = 0; p < nct; ++p) {
      const int ct = (p == 0) ? wv : 4;
      f32x4 acc = {};
#pragma unroll
      for (int kk = 0; kk < 4; ++kk) {
        half8 a  = *(const half8*)&Qs[fr][kk * 32 + kg8];
        half8 bb = *(const half8*)&Ks[ct * 16 + fr][kk * 32 + kg8];
        acc = MFMAH(a, bb, acc);
      }
#pragma unroll
      for (int r = 0; r < 4; ++r)
        sc[(lane >> 4) * 4 + r][ct * 16 + fr] = acc[r] * invscale;
    }
  }
  __syncthreads();

  // banded softmax; wave wv owns q-rows 4wv..4wv+3
#pragma unroll 1
  for (int rr = 0; rr < 4; ++rr) {
    const int r = wv * 4 + rr;
    const int c0 = lane;
    const bool ib0 = (c0 >= r);
    const bool ib1 = (lane <= r);
    float a0 = ib0 ? sc[r][c0] : -1e30f;
    float a1 = ib1 ? sc[r][64 + lane] : -1e30f;
    float mx = fmaxf(a0, a1);
#pragma unroll
    for (int o = 1; o < 64; o <<= 1) mx = fmaxf(mx, __shfl_xor(mx, o));
    float e0 = ib0 ? __expf(a0 - mx) : 0.f;
    float e1 = ib1 ? __expf(a1 - mx) : 0.f;
    float sm = e0 + e1;
#pragma unroll
    for (int o = 1; o < 64; o <<= 1) sm += __shfl_xor(sm, o);
    const float inv = 1.0f / sm;
    const float w0 = e0 * inv, w1 = e1 * inv;
    if (ib0) aw[r * 65 + (r + 64 - c0)] = w0;
    if (ib1) aw[r * 65 + (r - lane)] = w1;
    Ps[r][c0] = (_Float16)w0;
    if (lane < 32) Ps[r][64 + lane] = (_Float16)((lane < 16) ? w1 : 0.f);
  }
  __syncthreads();

  for (int i = tid; i < 1040; i += 256)
    attwg[(size_t)rowbase * 65 + i] = aw[i];

  // PV: C2[16 q][128 d] = P(16x96) @ V(96x128)
  f32x4 c2[2] = {};
#pragma unroll
  for (int kk = 0; kk < 3; ++kk) {
    half8 a = *(const half8*)&Ps[fr][kk * 32 + kg8];
#pragma unroll
    for (int dt2 = 0; dt2 < 2; ++dt2) {
      const int d = (2 * wv + dt2) * 16 + fr;
      half8 bb;
#pragma unroll
      for (int e = 0; e < 8; ++e) bb[e] = Vs[kk * 32 + kg8 + e][d];
      c2[dt2] = MFMAH(a, bb, c2[dt2]);
    }
  }
  // projection
#pragma unroll
  for (int r = 0; r < 4; ++r) {
    float p0 = 0.f, p1 = 0.f;
#pragma unroll
    for (int dt2 = 0; dt2 < 2; ++dt2) {
      const int d = (2 * wv + dt2) * 16 + fr;
      p0 += c2[dt2][r] * wol[d][0];
      p1 += c2[dt2][r] * wol[d][1];
    }
    p0 += __shfl_xor(p0, 1); p0 += __shfl_xor(p0, 2);
    p0 += __shfl_xor(p0, 4); p0 += __shfl_xor(p0, 8);
    p1 += __shfl_xor(p1, 1); p1 += __shfl_xor(p1, 2);
    p1 += __shfl_xor(p1, 4); p1 += __shfl_xor(p1, 8);
    if (fr == 0) {
      const int q = (lane >> 4) * 4 + r;
      proj[wv][q][0] = p0;
      proj[wv][q][1] = p1;
    }
  }
  __syncthreads();
  if (tid < 16) {
    float s0 = proj[0][tid][0] + proj[1][tid][0] + proj[2][tid][0] + proj[3][tid][0];
    float s1 = proj[0][tid][1] + proj[1][tid][1] + proj[2][tid][1] + proj[3][tid][1];
    outp[((size_t)rowbase + tid) * 2 + 0] = s0 * invscale + bo[0];
    outp[((size_t)rowbase + tid) * 2 + 1] = s1 * invscale + bo[1];
  }
}

extern "C" void kernel_launch(void* const* d_in, const int* in_sizes, int n_in,
                              void* d_out, int out_size, void* d_ws, size_t ws_size,
                              hipStream_t stream) {
  const float* x  = (const float*)d_in[0];
  const float* W1 = (const float*)d_in[1];
  const float* b1 = (const float*)d_in[2];
  const float* Wq = (const float*)d_in[3];
  const float* Wk = (const float*)d_in[4];
  const float* Wv = (const float*)d_in[5];
  const float* Wo = (const float*)d_in[6];
  const float* bo = (const float*)d_in[7];
  float* out  = (float*)d_out;            // (4,2048,2)
  float* attw = out + 16384;              // (4,2048,65)

  _Float16* W1t  = (_Float16*)d_ws;       // 128x2048
  _Float16* Wqkv = W1t + 262144;          // 3 x 128x128
  _Float16* Pe   = Wqkv + 49152;          // 2048x2048 pos-enc table
  _Float16* Qg   = Pe + 4194304;          // 8192x128
  _Float16* Kg   = Qg + 1048576;
  _Float16* Vg   = Kg + 1048576;

  k_prep<<<1280, 256, 0, stream>>>(W1, Wq, Wk, Wv, W1t, Wqkv, Pe);
  k_fused<<<512, 512, 0, stream>>>(x, W1t, Pe, Wqkv, b1, Qg, Kg, Vg);
  k_attn<<<512, 256, 0, stream>>>(Qg, Kg, Vg, Wo, bo, out, attw);
}

// Round 8
// 64.127 us; speedup vs baseline: 1.2278x; 1.0397x over previous
//
#include <hip/hip_runtime.h>
#include <hip/hip_bf16.h>

typedef __attribute__((ext_vector_type(8))) _Float16 half8;
typedef __attribute__((ext_vector_type(4))) _Float16 half4;
typedef __attribute__((ext_vector_type(4))) float f32x4;

#define MFMAH(a,b,c) __builtin_amdgcn_mfma_f32_16x16x32_f16(a,b,c,0,0,0)

#define LOG2_10K_64 0.2076205059304595f
#define INV2PI 0.15915494309189535f

__device__ __forceinline__ void gload_lds16(const void* g, void* l) {
  __builtin_amdgcn_global_load_lds((const __attribute__((address_space(1))) void*)g,
                                   (__attribute__((address_space(3))) void*)l,
                                   16, 0, 0);
}

// ---------------------------------------------------------------------------
// Prep: W1 -> W1t[n][k] f16; Wq/Wk/Wv -> transposed f16; Pe[2048][2048] f16
// pos-enc table. Grid: 64 transpose + 192 qkv + 1024 Pe blocks.
// ---------------------------------------------------------------------------
__global__ __launch_bounds__(256) void k_prep(const float* __restrict__ W1,
                                              const float* __restrict__ Wq,
                                              const float* __restrict__ Wk,
                                              const float* __restrict__ Wv,
                                              _Float16* __restrict__ W1t,
                                              _Float16* __restrict__ Wqkvt,
                                              _Float16* __restrict__ Pe) {
  const int bid = blockIdx.x, tid = threadIdx.x;
  if (bid < 64) {
    __shared__ float Tl[64][65];
    const int kt0 = (bid >> 1) * 64, nt0 = (bid & 1) * 64;
    const int row = tid >> 2, c0 = (tid & 3) * 16;
#pragma unroll
    for (int e = 0; e < 16; e += 4) {
      float4 f = *(const float4*)(W1 + (size_t)(kt0 + row) * 128 + nt0 + c0 + e);
      Tl[row][c0 + e] = f.x; Tl[row][c0 + e + 1] = f.y;
      Tl[row][c0 + e + 2] = f.z; Tl[row][c0 + e + 3] = f.w;
    }
    __syncthreads();
    const int nrow = tid >> 2, kc0 = (tid & 3) * 16;
    _Float16* wp = W1t + (size_t)(nt0 + nrow) * 2048 + kt0 + kc0;
#pragma unroll
    for (int e = 0; e < 16; ++e) wp[e] = (_Float16)Tl[kc0 + e][nrow];
  } else if (bid < 256) {
    int r = (bid - 64) * 256 + tid;
    if (r < 3 * 16384) {
      int m = r >> 14, e = r & 16383;
      int n = e >> 7, k = e & 127;
      const float* W = (m == 0) ? Wq : (m == 1) ? Wk : Wv;
      Wqkvt[r] = (_Float16)W[k * 128 + n];
    }
  } else {
    const int g = (bid - 256) * 256 + tid;      // 0..262143
    const int s = g >> 7;
    const int j0 = (g & 127) * 16;
    const float sf = (float)s;
    half8 o0, o1;
#pragma unroll
    for (int p = 0; p < 8; ++p) {
      const int jh = (j0 >> 1) + p;
      float c = exp2f((float)jh * -LOG2_10K_64) * INV2PI;
      float r = __builtin_fmaf(sf, c, -rintf(sf * c));
      _Float16 sn = (_Float16)__builtin_amdgcn_sinf(r);
      _Float16 cs = (_Float16)__builtin_amdgcn_cosf(r);
      if (p < 4) { o0[2 * p] = sn; o0[2 * p + 1] = cs; }
      else       { o1[2 * (p - 4)] = sn; o1[2 * (p - 4) + 1] = cs; }
    }
    _Float16* dst = Pe + (size_t)s * 2048 + j0;
    *(half8*)dst = o0;
    *(half8*)(dst + 8) = o1;
  }
}

// ---------------------------------------------------------------------------
// Fused GEMM1 + QKV with global_load_lds staging (no VGPR round-trip).
// Block = 16 rows x full K; 8 waves, wave wv owns output cols wv*16..+15.
// Per 256-k chunk: stage raw x (fp32, 16 KB) + Pe (f16, 8 KB) to LDS via
// gload_lds with pre-swizzled SOURCE addrs (32B-XOR for x, 16B-XOR for Pe);
// waves build A-frags (x+Pe -> f16) from LDS and stream B from n-major W1t
// (L2). T3 minimum-2-phase: stage(next); compute(cur); barrier.
// Grid 512, 512 thr, LDS 48 KB -> 2 blocks/CU.
// ---------------------------------------------------------------------------
__global__ __launch_bounds__(512) void k_fused(const float* __restrict__ x,
                                               const _Float16* __restrict__ W1t,
                                               const _Float16* __restrict__ Pe,
                                               const _Float16* __restrict__ Wqkv,
                                               const float* __restrict__ b1,
                                               _Float16* __restrict__ Qg,
                                               _Float16* __restrict__ Kg,
                                               _Float16* __restrict__ Vg) {
  __shared__ __align__(16) char smem[49152];
  // Ax[buf]: 16 rows x 1024 B fp32   at buf*16384
  // Pl[buf]: 16 rows x 512 B  f16    at 32768 + buf*8192
  const int tid = threadIdx.x;
  const int lane = tid & 63, wv = tid >> 6;
  const int fr = lane & 15, hi = lane >> 4;
  const int i0 = blockIdx.x * 16;

  // per-lane swizzled source addresses (bases; advance by chunk)
  const int xR0 = wv;                 // x row for instr 0
  const int xR1 = wv + 8;             // x row for instr 1
  const int xu0 = ((lane >> 1) ^ (xR0 & 7)) * 8 + (lane & 1) * 4;
  const int xu1 = ((lane >> 1) ^ (xR1 & 7)) * 8 + (lane & 1) * 4;
  const int pr  = 2 * wv + (lane >> 5);
  const int pu  = ((lane & 31) ^ (pr & 7)) * 8;
  const float*    xsrc0 = x + (size_t)(i0 + xR0) * 2048 + xu0;
  const float*    xsrc1 = x + (size_t)(i0 + xR1) * 2048 + xu1;
  const _Float16* psrc  = Pe + (size_t)((i0 + pr) & 2047) * 2048 + pu;
  char* xdst0 = smem + xR0 * 1024;
  char* xdst1 = smem + xR1 * 1024;
  char* pdst  = smem + 32768 + 2 * wv * 512;

  auto stage = [&](int buf, int c) {
    const int kc = c * 256;
    gload_lds16(xsrc0 + kc, xdst0 + buf * 16384);
    gload_lds16(xsrc1 + kc, xdst1 + buf * 16384);
    gload_lds16(psrc + kc, pdst + buf * 8192);
  };

  const _Float16* brow = W1t + (size_t)(wv * 16 + fr) * 2048 + hi * 8;
  const int sw = fr & 7;
  const char* axb = smem + fr * 1024;
  const char* plb = smem + 32768 + fr * 512;

  stage(0, 0);
  __syncthreads();                       // drains vmcnt(0) -> buf0 ready

  f32x4 acc = {};
#pragma unroll 1
  for (int c = 0; c < 8; ++c) {
    const int cur = c & 1;
    if (c < 7) stage(cur ^ 1, c + 1);
    const char* axc = axb + cur * 16384;
    const char* plc = plb + cur * 8192;
#pragma unroll
    for (int ks = 0; ks < 8; ++ks) {
      const int u = (ks * 4 + hi) ^ sw;
      f32x4 x0 = *(const f32x4*)(axc + u * 32);
      f32x4 x1 = *(const f32x4*)(axc + u * 32 + 16);
      half8 pe = *(const half8*)(plc + u * 16);
      half8 af;
#pragma unroll
      for (int e = 0; e < 4; ++e) af[e] = (_Float16)(x0[e] + (float)pe[e]);
#pragma unroll
      for (int e = 0; e < 4; ++e) af[4 + e] = (_Float16)(x1[e] + (float)pe[4 + e]);
      half8 b = *(const half8*)(brow + c * 256 + ks * 32);
      acc = MFMAH(af, b, acc);
    }
    __syncthreads();                     // drains stage(c+1) + all reads
  }

  // epilogue: bias+relu -> Hs f16 (overlay), then QKV from global Wqkv
  _Float16 (*Hs)[136] = (_Float16(*)[136])smem;
  {
    const int col = wv * 16 + fr;
    const float bv = b1[col];
#pragma unroll
    for (int r = 0; r < 4; ++r) {
      float v = acc[r] + bv;
      v = v > 0.f ? v : 0.f;
      Hs[hi * 4 + r][col] = (_Float16)v;
    }
  }
  __syncthreads();
  const _Float16* wqrow = Wqkv + (size_t)(wv * 16 + fr) * 128 + hi * 8;
#pragma unroll 1
  for (int m = 0; m < 3; ++m) {
    f32x4 a2 = {};
#pragma unroll
    for (int kk = 0; kk < 4; ++kk) {
      half8 a = *(const half8*)&Hs[fr][kk * 32 + hi * 8];
      half8 b = *(const half8*)(wqrow + m * 16384 + kk * 32);
      a2 = MFMAH(a, b, a2);
    }
    _Float16* dst = (m == 0) ? Qg : (m == 1) ? Kg : Vg;
#pragma unroll
    for (int r = 0; r < 4; ++r)
      dst[(size_t)(i0 + hi * 4 + r) * 128 + wv * 16 + fr] = (_Float16)a2[r];
  }
}

// ---------------------------------------------------------------------------
// Attention via MFMA. Block = 16 q-rows of one batch; 4 waves; grid 512.
// Zero K-rows outside sequence -> score 0 (included), matching reference.
// ---------------------------------------------------------------------------
__global__ __launch_bounds__(256) void k_attn(const _Float16* __restrict__ Qg,
                                              const _Float16* __restrict__ Kg,
                                              const _Float16* __restrict__ Vg,
                                              const float* __restrict__ Wo,
                                              const float* __restrict__ bo,
                                              float* __restrict__ outp,
                                              float* __restrict__ attwg) {
  __shared__ _Float16 Qs[16][136];
  __shared__ _Float16 Ks[80][136];
  __shared__ _Float16 Vs[96][136];
  __shared__ _Float16 Ps[16][104];
  __shared__ float sc[16][84];
  __shared__ float aw[16 * 65];
  __shared__ float wol[128][2];
  __shared__ float proj[4][16][2];
  const int tid = threadIdx.x;
  const int lane = tid & 63, wv = tid >> 6;
  const int b = blockIdx.x >> 7;
  const int i0 = (blockIdx.x & 127) << 4;
  const int rowbase = b * 2048 + i0;
  const float invscale = 0.08838834764831845f;  // 1/sqrt(128)

  {
    const int row = tid >> 4, d8 = (tid & 15) * 8;
    *(half8*)&Qs[row][d8] = *(const half8*)(Qg + (size_t)(rowbase + row) * 128 + d8);
  }
#pragma unroll
  for (int it = 0; it < 5; ++it) {
    const int idx = it * 256 + tid;
    const int lr = idx >> 4, d8 = (idx & 15) * 8;
    const int j = i0 - 32 + lr;
    half8 kv = {0, 0, 0, 0, 0, 0, 0, 0};
    if (j >= 0 && j < 2048)
      kv = *(const half8*)(Kg + (size_t)(b * 2048 + j) * 128 + d8);
    *(half8*)&Ks[lr][d8] = kv;
  }
#pragma unroll
  for (int it = 0; it < 6; ++it) {
    const int idx = it * 256 + tid;
    const int lr = idx >> 4, d8 = (idx & 15) * 8;
    const int j = i0 - 32 + lr;
    half8 vv = {0, 0, 0, 0, 0, 0, 0, 0};
    if (lr < 80 && j >= 0 && j < 2048)
      vv = *(const half8*)(Vg + (size_t)(b * 2048 + j) * 128 + d8);
    *(half8*)&Vs[lr][d8] = vv;
  }
  wol[tid >> 1][tid & 1] = Wo[tid];
  __syncthreads();

  const int fr = lane & 15, kg8 = (lane >> 4) * 8;
  // QK^T: C[16 q][80 k] = 5 col-tiles
  {
    const int nct = (wv == 0) ? 2 : 1;
    for (int p = 0; p < nct; ++p) {
      const int ct = (p == 0) ? wv : 4;
      f32x4 acc = {};
#pragma unroll
      for (int kk = 0; kk < 4; ++kk) {
        half8 a  = *(const half8*)&Qs[fr][kk * 32 + kg8];
        half8 bb = *(const half8*)&Ks[ct * 16 + fr][kk * 32 + kg8];
        acc = MFMAH(a, bb, acc);
      }
#pragma unroll
      for (int r = 0; r < 4; ++r)
        sc[(lane >> 4) * 4 + r][ct * 16 + fr] = acc[r] * invscale;
    }
  }
  __syncthreads();

  // banded softmax; wave wv owns q-rows 4wv..4wv+3
#pragma unroll 1
  for (int rr = 0; rr < 4; ++rr) {
    const int r = wv * 4 + rr;
    const int c0 = lane;
    const bool ib0 = (c0 >= r);
    const bool ib1 = (lane <= r);
    float a0 = ib0 ? sc[r][c0] : -1e30f;
    float a1 = ib1 ? sc[r][64 + lane] : -1e30f;
    float mx = fmaxf(a0, a1);
#pragma unroll
    for (int o = 1; o < 64; o <<= 1) mx = fmaxf(mx, __shfl_xor(mx, o));
    float e0 = ib0 ? __expf(a0 - mx) : 0.f;
    float e1 = ib1 ? __expf(a1 - mx) : 0.f;
    float sm = e0 + e1;
#pragma unroll
    for (int o = 1; o < 64; o <<= 1) sm += __shfl_xor(sm, o);
    const float inv = 1.0f / sm;
    const float w0 = e0 * inv, w1 = e1 * inv;
    if (ib0) aw[r * 65 + (r + 64 - c0)] = w0;
    if (ib1) aw[r * 65 + (r - lane)] = w1;
    Ps[r][c0] = (_Float16)w0;
    if (lane < 32) Ps[r][64 + lane] = (_Float16)((lane < 16) ? w1 : 0.f);
  }
  __syncthreads();

  for (int i = tid; i < 1040; i += 256)
    attwg[(size_t)rowbase * 65 + i] = aw[i];

  // PV: C2[16 q][128 d] = P(16x96) @ V(96x128)
  f32x4 c2[2] = {};
#pragma unroll
  for (int kk = 0; kk < 3; ++kk) {
    half8 a = *(const half8*)&Ps[fr][kk * 32 + kg8];
#pragma unroll
    for (int dt2 = 0; dt2 < 2; ++dt2) {
      const int d = (2 * wv + dt2) * 16 + fr;
      half8 bb;
#pragma unroll
      for (int e = 0; e < 8; ++e) bb[e] = Vs[kk * 32 + kg8 + e][d];
      c2[dt2] = MFMAH(a, bb, c2[dt2]);
    }
  }
  // projection
#pragma unroll
  for (int r = 0; r < 4; ++r) {
    float p0 = 0.f, p1 = 0.f;
#pragma unroll
    for (int dt2 = 0; dt2 < 2; ++dt2) {
      const int d = (2 * wv + dt2) * 16 + fr;
      p0 += c2[dt2][r] * wol[d][0];
      p1 += c2[dt2][r] * wol[d][1];
    }
    p0 += __shfl_xor(p0, 1); p0 += __shfl_xor(p0, 2);
    p0 += __shfl_xor(p0, 4); p0 += __shfl_xor(p0, 8);
    p1 += __shfl_xor(p1, 1); p1 += __shfl_xor(p1, 2);
    p1 += __shfl_xor(p1, 4); p1 += __shfl_xor(p1, 8);
    if (fr == 0) {
      const int q = (lane >> 4) * 4 + r;
      proj[wv][q][0] = p0;
      proj[wv][q][1] = p1;
    }
  }
  __syncthreads();
  if (tid < 16) {
    float s0 = proj[0][tid][0] + proj[1][tid][0] + proj[2][tid][0] + proj[3][tid][0];
    float s1 = proj[0][tid][1] + proj[1][tid][1] + proj[2][tid][1] + proj[3][tid][1];
    outp[((size_t)rowbase + tid) * 2 + 0] = s0 * invscale + bo[0];
    outp[((size_t)rowbase + tid) * 2 + 1] = s1 * invscale + bo[1];
  }
}

extern "C" void kernel_launch(void* const* d_in, const int* in_sizes, int n_in,
                              void* d_out, int out_size, void* d_ws, size_t ws_size,
                              hipStream_t stream) {
  const float* x  = (const float*)d_in[0];
  const float* W1 = (const float*)d_in[1];
  const float* b1 = (const float*)d_in[2];
  const float* Wq = (const float*)d_in[3];
  const float* Wk = (const float*)d_in[4];
  const float* Wv = (const float*)d_in[5];
  const float* Wo = (const float*)d_in[6];
  const float* bo = (const float*)d_in[7];
  float* out  = (float*)d_out;            // (4,2048,2)
  float* attw = out + 16384;              // (4,2048,65)

  _Float16* W1t  = (_Float16*)d_ws;       // 128x2048
  _Float16* Wqkv = W1t + 262144;          // 3 x 128x128
  _Float16* Pe   = Wqkv + 49152;          // 2048x2048 pos-enc table
  _Float16* Qg   = Pe + 4194304;          // 8192x128
  _Float16* Kg   = Qg + 1048576;
  _Float16* Vg   = Kg + 1048576;

  k_prep<<<1280, 256, 0, stream>>>(W1, Wq, Wk, Wv, W1t, Wqkv, Pe);
  k_fused<<<512, 512, 0, stream>>>(x, W1t, Pe, Wqkv, b1, Qg, Kg, Vg);
  k_attn<<<512, 256, 0, stream>>>(Qg, Kg, Vg, Wo, bo, out, attw);
}